// Round 1
// baseline (1003.153 us; speedup 1.0000x reference)
//
#include <hip/hip_runtime.h>
#include <math.h>

#define BB 256
#define SS 512
#define VV 768
#define TT 513   // S+1
#define HH 50

// workspace layout (float offsets)
#define OFF_M1    0
#define OFF_M2    (OFF_M1 + BB*VV)                    // 196608
#define OFF_XPART (OFF_M2 + BB*VV)                    // 393216 ; 4 parts x B x 772
#define XPART_STRIDE 772
#define OFF_AROW  (OFF_XPART + 4*BB*XPART_STRIDE)     // 1183744 ; stride 520 per b
#define AROW_STRIDE 520
#define OFF_COLM  (OFF_AROW + BB*AROW_STRIDE)         // 1316864
#define OFF_COLRD (OFF_COLM + 520)                    // 1317384
#define OFF_YPART (OFF_COLRD + 520)                   // 1317904 ; 4 parts x B x V
// total = 2,104,336 floats = 8.42 MB

// ---------------- K1: means (atomic partial sums, 4 s-chunks per (tensor,b)) ---
__global__ __launch_bounds__(192) void k_mean(const float* __restrict__ o1,
                                              const float* __restrict__ o2,
                                              float* __restrict__ ws) {
    int bid   = blockIdx.x;            // ((tensor*B)+b)*4 + chunk
    int chunk = bid & 3;
    int b     = (bid >> 2) & (BB - 1);
    int tensor = bid >> 10;
    const float* src = tensor ? o2 : o1;
    float* dst = ws + (tensor ? OFF_M2 : OFF_M1) + b * VV;
    int tid = threadIdx.x;             // 0..191, one float4 column each
    const float4* p = (const float4*)(src + (size_t)b * SS * VV + (size_t)chunk * 128 * VV) + tid;
    float4 acc = {0.f, 0.f, 0.f, 0.f};
#pragma unroll 4
    for (int s = 0; s < 128; ++s) {
        float4 x = p[(size_t)s * 192];
        acc.x += x.x; acc.y += x.y; acc.z += x.z; acc.w += x.w;
    }
    const float inv = 1.0f / 512.0f;
    float* d4 = dst + tid * 4;
    atomicAdd(d4 + 0, acc.x * inv);
    atomicAdd(d4 + 1, acc.y * inv);
    atomicAdd(d4 + 2, acc.z * inv);
    atomicAdd(d4 + 3, acc.w * inv);
}

// ---------------- K2: x-side online softmax over s (per (b, quarter)) ---------
#define XCHUNK 8
__global__ __launch_bounds__(256) void k_xside(const float* __restrict__ o1,
                                               float* __restrict__ ws) {
    int part = blockIdx.x & 3;
    int b    = blockIdx.x >> 2;
    int tid  = threadIdx.x;
    int wave = tid >> 6, lane = tid & 63;
    __shared__ __align__(16) float m2s[VV];
    __shared__ __align__(16) float tile[XCHUNK][VV];
    __shared__ float sc[XCHUNK];

    const float* m2p = ws + OFF_M2 + b * VV;
    for (int i = tid; i < VV; i += 256) m2s[i] = m2p[i];
    __syncthreads();

    float accv[3] = {0.f, 0.f, 0.f};
    float M = -1e30f, d = 0.f;
    int s0 = part * 128;
    const float* base = o1 + (size_t)b * SS * VV;

    for (int c = 0; c < 128 / XCHUNK; ++c) {
        // stage XCHUNK rows into LDS (256 threads x 6 float4)
        const float4* g = (const float4*)(base + (size_t)(s0 + c * XCHUNK) * VV);
        float4* l4 = (float4*)&tile[0][0];
#pragma unroll
        for (int k = 0; k < 6; ++k) l4[k * 256 + tid] = g[k * 256 + tid];
        __syncthreads();
        // scores: wave w computes rows 2w, 2w+1
#pragma unroll
        for (int r2 = 0; r2 < 2; ++r2) {
            int r = wave * 2 + r2;
            float p = 0.f;
#pragma unroll
            for (int k = 0; k < 12; ++k) p += tile[r][lane + 64 * k] * m2s[lane + 64 * k];
#pragma unroll
            for (int off = 32; off > 0; off >>= 1) p += __shfl_down(p, off);
            if (lane == 0) sc[r] = p;
        }
        __syncthreads();
        float sv[XCHUNK], cmax = -1e30f;
#pragma unroll
        for (int j = 0; j < XCHUNK; ++j) { sv[j] = sc[j]; cmax = fmaxf(cmax, sv[j]); }
        float newM  = fmaxf(M, cmax);
        float scale = __expf(M - newM);
        float w[XCHUNK], wsum = 0.f;
#pragma unroll
        for (int j = 0; j < XCHUNK; ++j) { w[j] = __expf(sv[j] - newM); wsum += w[j]; }
        d = d * scale + wsum;
#pragma unroll
        for (int i = 0; i < 3; ++i) {
            int v = tid + 256 * i;
            float a = accv[i] * scale;
#pragma unroll
            for (int j = 0; j < XCHUNK; ++j) a += w[j] * tile[j][v];
            accv[i] = a;
        }
        M = newM;
        __syncthreads();
    }

    if (part == 3) {  // virtual mean row: data = m1[b], score = m1.m2
        const float* m1p = ws + OFF_M1 + b * VV;
        for (int i = tid; i < VV; i += 256) tile[0][i] = m1p[i];
        __syncthreads();
        if (wave == 0) {
            float p = 0.f;
#pragma unroll
            for (int k = 0; k < 12; ++k) p += tile[0][lane + 64 * k] * m2s[lane + 64 * k];
#pragma unroll
            for (int off = 32; off > 0; off >>= 1) p += __shfl_down(p, off);
            if (lane == 0) sc[0] = p;
        }
        __syncthreads();
        float s0v   = sc[0];
        float newM  = fmaxf(M, s0v);
        float scale = __expf(M - newM);
        float w0    = __expf(s0v - newM);
        d = d * scale + w0;
#pragma unroll
        for (int i = 0; i < 3; ++i) {
            int v = tid + 256 * i;
            accv[i] = accv[i] * scale + w0 * tile[0][v];
        }
        M = newM;
    }

    float* outp = ws + OFF_XPART + (size_t)(part * BB + b) * XPART_STRIDE;
#pragma unroll
    for (int i = 0; i < 3; ++i) outp[tid + 256 * i] = accv[i];
    if (tid == 0) { outp[768] = M; outp[769] = d; }
}

// ---------------- K3: y-side scores a_row[b,t] = m1[b].x2[b,t] -----------------
__global__ __launch_bounds__(256) void k_yscore(const float* __restrict__ o2,
                                                float* __restrict__ ws) {
    int bid = blockIdx.x;              // b*8 + tc
    int tc = bid & 7, b = bid >> 3;
    int wave = threadIdx.x >> 6, lane = threadIdx.x & 63;
    const float4* m14 = (const float4*)(ws + OFF_M1 + b * VV);
    float4 mf[3];
#pragma unroll
    for (int k = 0; k < 3; ++k) mf[k] = m14[lane + 64 * k];
    const float* base = o2 + (size_t)b * SS * VV;
    float* arow = ws + OFF_AROW + b * AROW_STRIDE;
    for (int i = 0; i < 16; ++i) {
        int t = tc * 64 + wave * 16 + i;
        const float4* r4 = (const float4*)(base + (size_t)t * VV);
        float p = 0.f;
#pragma unroll
        for (int k = 0; k < 3; ++k) {
            float4 x = r4[lane + 64 * k];
            p += x.x * mf[k].x + x.y * mf[k].y + x.z * mf[k].z + x.w * mf[k].w;
        }
#pragma unroll
        for (int off = 32; off > 0; off >>= 1) p += __shfl_down(p, off);
        if (lane == 0) arow[t] = p;
    }
    if (tc == 7 && wave == 0) {        // t = S: row is m2[b]
        const float4* r4 = (const float4*)(ws + OFF_M2 + b * VV);
        float p = 0.f;
#pragma unroll
        for (int k = 0; k < 3; ++k) {
            float4 x = r4[lane + 64 * k];
            p += x.x * mf[k].x + x.y * mf[k].y + x.z * mf[k].z + x.w * mf[k].w;
        }
#pragma unroll
        for (int off = 32; off > 0; off >>= 1) p += __shfl_down(p, off);
        if (lane == 0) arow[SS] = p;
    }
}

// ---------------- K4: per-column (t) softmax stats over b ----------------------
__global__ __launch_bounds__(256) void k_colstats(float* __restrict__ ws) {
    int t = blockIdx.x;                // 0..512
    int tid = threadIdx.x;             // thread = b
    int wave = tid >> 6, lane = tid & 63;
    float v = ws[OFF_AROW + tid * AROW_STRIDE + t];
    __shared__ float red[4], red2[4];
    float m = v;
#pragma unroll
    for (int off = 32; off > 0; off >>= 1) m = fmaxf(m, __shfl_down(m, off));
    if (lane == 0) red[wave] = m;
    __syncthreads();
    float m0 = fmaxf(fmaxf(red[0], red[1]), fmaxf(red[2], red[3]));
    float e = __expf(v - m0);
#pragma unroll
    for (int off = 32; off > 0; off >>= 1) e += __shfl_down(e, off);
    if (lane == 0) red2[wave] = e;
    __syncthreads();
    if (tid == 0) {
        float D = red2[0] + red2[1] + red2[2] + red2[3];
        ws[OFF_COLM + t]  = m0;
        ws[OFF_COLRD + t] = 1.0f / D;
    }
}

// ---------------- K5: y-side weighted sum over t (per (b, quarter)) ------------
__global__ __launch_bounds__(192) void k_yweight(const float* __restrict__ o2,
                                                 float* __restrict__ ws) {
    int part = blockIdx.x & 3, b = blockIdx.x >> 2;
    int tid = threadIdx.x;             // 0..191, one float4 column each
    __shared__ float wl[129];
    int t0 = part * 128;
    const float* arow = ws + OFF_AROW + b * AROW_STRIDE;
    for (int i = tid; i < 129; i += 192) {
        if (i < 128) {
            int t = t0 + i;
            wl[i] = __expf(arow[t] - ws[OFF_COLM + t]) * ws[OFF_COLRD + t];
        } else if (part == 3) {
            wl[128] = __expf(arow[SS] - ws[OFF_COLM + SS]) * ws[OFF_COLRD + SS];
        }
    }
    __syncthreads();
    const float4* base = (const float4*)(o2 + (size_t)b * SS * VV) + tid;
    float4 acc = {0.f, 0.f, 0.f, 0.f};
    for (int i = 0; i < 128; ++i) {
        float w = wl[i];
        float4 x = base[(size_t)(t0 + i) * 192];
        acc.x += w * x.x; acc.y += w * x.y; acc.z += w * x.z; acc.w += w * x.w;
    }
    if (part == 3) {
        float w = wl[128];
        float4 x = ((const float4*)(ws + OFF_M2 + b * VV))[tid];
        acc.x += w * x.x; acc.y += w * x.y; acc.z += w * x.z; acc.w += w * x.w;
    }
    ((float4*)(ws + OFF_YPART + (size_t)(part * BB + b) * VV))[tid] = acc;
}

// ---------------- K6: epilogue — merge partials, GEMVs, MLP, sigmoid -----------
__global__ __launch_bounds__(256) void k_epilogue(const float* __restrict__ Wg,
                                                  const float* __restrict__ bg,
                                                  const float* __restrict__ Wfd,
                                                  const float* __restrict__ bfd,
                                                  const float* __restrict__ Wff,
                                                  const float* __restrict__ bff,
                                                  float* __restrict__ ws,
                                                  float* __restrict__ out) {
    int b = blockIdx.x;
    int tid = threadIdx.x;
    __shared__ __align__(16) float cx[2 * VV];   // [m1 | atty]  (for o1)
    __shared__ __align__(16) float cy[2 * VV];   // [m2 | attx]  (for o2)
    __shared__ float od[2][HH][2];
    __shared__ float o1s[HH], o2s[HH];

    // x-partial merge factors (redundant per thread, cheap)
    float Mp[4], dp[4];
#pragma unroll
    for (int p = 0; p < 4; ++p) {
        const float* xp = ws + OFF_XPART + (size_t)(p * BB + b) * XPART_STRIDE;
        Mp[p] = xp[768];
        dp[p] = xp[769];
    }
    float M = fmaxf(fmaxf(Mp[0], Mp[1]), fmaxf(Mp[2], Mp[3]));
    float e[4], den = 0.f;
#pragma unroll
    for (int p = 0; p < 4; ++p) { e[p] = __expf(Mp[p] - M); den += dp[p] * e[p]; }
    float rden = 1.0f / den;

    for (int i = tid; i < VV; i += 256) {
        cx[i] = ws[OFF_M1 + b * VV + i];
        cy[i] = ws[OFF_M2 + b * VV + i];
        float ay = 0.f;
#pragma unroll
        for (int p = 0; p < 4; ++p) ay += ws[OFF_YPART + (size_t)(p * BB + b) * VV + i];
        cx[VV + i] = ay;
        float ax = 0.f;
#pragma unroll
        for (int p = 0; p < 4; ++p) ax += ws[OFF_XPART + (size_t)(p * BB + b) * XPART_STRIDE + i] * e[p];
        cy[VV + i] = ax * rden;
    }
    __syncthreads();

    // o1/o2 GEMV: 200 tasks = which(2) x h(50) x seg(2), each a 768-dot
    if (tid < 200) {
        int which = tid / 100, r = tid % 100, h = r >> 1, seg = r & 1;
        const float* c = which ? cy : cx;
        const float4* cc = (const float4*)(c + seg * VV);
        const float4* wg = (const float4*)(Wg + (size_t)h * 2 * VV + seg * VV);
        float acc = 0.f;
        for (int j = 0; j < VV / 4; ++j) {
            float4 a4 = cc[j]; float4 w4 = wg[j];
            acc += a4.x * w4.x + a4.y * w4.y + a4.z * w4.z + a4.w * w4.w;
        }
        od[which][h][seg] = acc;
    }
    __syncthreads();
    if (tid < HH)                     o1s[tid]      = od[0][tid][0]    + od[0][tid][1]    + bg[tid];
    else if (tid >= 64 && tid < 64 + HH) { int h = tid - 64; o2s[h] = od[1][h][0] + od[1][h][1] + bg[h]; }
    __syncthreads();
    if (tid < 64) {
        float hv = 0.f;
        if (tid < HH) {
            float a = bfd[tid];
            for (int k = 0; k < HH; ++k)
                a += o1s[k] * Wfd[tid * 2 * HH + k] + o2s[k] * Wfd[tid * 2 * HH + HH + k];
            hv = fmaxf(a, 0.f) * Wff[tid];
        }
#pragma unroll
        for (int off = 32; off > 0; off >>= 1) hv += __shfl_down(hv, off);
        if (tid == 0) out[b] = 1.0f / (1.0f + __expf(-(hv + bff[0])));
    }
}

extern "C" void kernel_launch(void* const* d_in, const int* in_sizes, int n_in,
                              void* d_out, int out_size, void* d_ws, size_t ws_size,
                              hipStream_t stream) {
    const float* o1  = (const float*)d_in[0];
    const float* o2  = (const float*)d_in[1];
    const float* Wg  = (const float*)d_in[2];
    const float* bg  = (const float*)d_in[3];
    const float* Wfd = (const float*)d_in[4];
    const float* bfd = (const float*)d_in[5];
    const float* Wff = (const float*)d_in[6];
    const float* bff = (const float*)d_in[7];
    float* out = (float*)d_out;
    float* ws  = (float*)d_ws;

    // zero m1/m2 (atomic accumulation targets)
    hipMemsetAsync(ws, 0, (size_t)2 * BB * VV * sizeof(float), stream);

    k_mean    <<<2048, 192, 0, stream>>>(o1, o2, ws);
    k_xside   <<<1024, 256, 0, stream>>>(o1, ws);
    k_yscore  <<<2048, 256, 0, stream>>>(o2, ws);
    k_colstats<<< 513, 256, 0, stream>>>(ws);
    k_yweight <<<1024, 192, 0, stream>>>(o2, ws);
    k_epilogue<<< 256, 256, 0, stream>>>(Wg, bg, Wfd, bfd, Wff, bff, ws, out);
}